// Round 5
// baseline (453.397 us; speedup 1.0000x reference)
//
#include <hip/hip_runtime.h>
#include <hip/hip_cooperative_groups.h>
#include <hip/hip_bf16.h>
#include <stdint.h>

namespace cg = cooperative_groups;

// Problem constants: B=4, S=2048, H=1024
#define BATCH 4
#define SLEN  2048
#define HID   1024

typedef __attribute__((ext_vector_type(8))) short bfrag8;   // 8 bf16 (4 VGPRs)
typedef __attribute__((ext_vector_type(4))) float facc4;    // 4 fp32 acc
typedef __attribute__((ext_vector_type(4))) unsigned short us4;

__device__ __forceinline__ unsigned short f2b(float f) {
  union { float f; unsigned int i; } x; x.f = f;
  unsigned int r = x.i + 0x7FFFu + ((x.i >> 16) & 1u);  // RNE
  return (unsigned short)(r >> 16);
}

__device__ __forceinline__ void gl_lds16(const void* g, void* l) {
  __builtin_amdgcn_global_load_lds(
      (const __attribute__((address_space(1))) void*)g,
      (__attribute__((address_space(3))) void*)l, 16, 0, 0);
}

// ==================== shared device bodies (used by fused + fallback) ======

// ---- cast body: i-th us4 of the concatenated inputs -> bf16 workspace ----
__device__ __forceinline__ void cast_elem(
    long i, const float* __restrict__ q, const float* __restrict__ k,
    const float* __restrict__ v, const float* __restrict__ wq,
    const float* __restrict__ wk, const float* __restrict__ wv,
    us4* __restrict__ dst) {
  const long S1 = 2097152, S2 = 4194304, S3 = 6291456,
             S4 = 6553600, S5 = 6815744;
  const float4* src; long off;
  if (i < S2) {
    if (i < S1) { src = (const float4*)q;  off = i; }
    else        { src = (const float4*)k;  off = i - S1; }
  } else if (i < S3) { src = (const float4*)v;  off = i - S2; }
  else if   (i < S4) { src = (const float4*)wq; off = i - S3; }
  else if   (i < S5) { src = (const float4*)wk; off = i - S4; }
  else               { src = (const float4*)wv; off = i - S5; }
  float4 x = src[off];
  us4 o;
  o.x = f2b(x.x); o.y = f2b(x.y); o.z = f2b(x.z); o.w = f2b(x.w);
  dst[i] = o;
}

// ---- one 128^2 proj job (r0-proven core; 912 TF, MfmaUtil 37%) -----------
// tid in [0,256). Safe for two half-units sharing one 512-thread block:
// control flow (and barrier count) is identical for all tids; only data
// (p2) differs, and the g-decode branches contain no barriers.
__device__ __forceinline__ void proj_job(
    int p2, int tid,
    unsigned short* __restrict__ As, unsigned short* __restrict__ Bs,
    const unsigned short* __restrict__ Xq, const unsigned short* __restrict__ Wqb,
    const unsigned short* __restrict__ Xk, const unsigned short* __restrict__ Wkb,
    const unsigned short* __restrict__ Xv, const unsigned short* __restrict__ Wvb,
    unsigned short* __restrict__ Qb, unsigned short* __restrict__ Kb,
    unsigned short* __restrict__ Vt) {
  const int g      = p2 >> 9;                       // 0:Q 1:K 2:Vt
  const int within = p2 & 511;

  const unsigned short* A; const unsigned short* B; unsigned short* C;
  long bm, bn; int ldc_;
  if (g == 0)      { A = Xq; B = Wqb; C = Qb; }
  else if (g == 1) { A = Xk; B = Wkb; C = Kb; }
  else             { A = Wvb; B = Xv; C = Vt; }
  if (g < 2) {   // nbm=64, nbn=8, GROUP=4
    const int gid = within >> 5, rem = within & 31;
    bm = (long)(gid * 4 + (rem & 3)) * 128;
    bn = (long)(rem >> 2) * 128;
    ldc_ = 1024;
  } else {       // nbm=8, nbn=64, GROUP=4
    const int gid = within >> 8, rem = within & 255;
    bm = (long)(gid * 4 + (rem & 3)) * 128;
    bn = (long)(rem >> 2) * 128;
    ldc_ = 8192;
  }

  const int lane = tid & 63;
  const int wave = tid >> 6;
  const int wr   = (wave >> 1) * 64;
  const int wc   = (wave & 1) * 64;
  const int ln   = lane & 15;
  const int lq   = lane >> 4;
  const int swz  = ln & 7;

  facc4 acc[4][4] = {};

  const unsigned short* ap[4]; const unsigned short* bp[4];
  unsigned short* asd[4]; unsigned short* bsd[4];
#pragma unroll
  for (int j = 0; j < 4; ++j) {
    const int c   = j * 256 + tid;
    const int row = c >> 3;
    const int src = ((c & 7) ^ (row & 7)) * 8;
    ap[j]  = A + (bm + row) * 1024 + src;
    bp[j]  = B + (bn + row) * 1024 + src;
    asd[j] = &As[c * 8];
    bsd[j] = &Bs[c * 8];
  }

  for (int k0 = 0; k0 < 1024; k0 += 64) {
#pragma unroll
    for (int j = 0; j < 4; ++j) { gl_lds16(ap[j], asd[j]); ap[j] += 64; }
#pragma unroll
    for (int j = 0; j < 4; ++j) { gl_lds16(bp[j], bsd[j]); bp[j] += 64; }
    __syncthreads();

#pragma unroll
    for (int kk = 0; kk < 2; ++kk) {
      bfrag8 af[4], bfr[4];
#pragma unroll
      for (int i = 0; i < 4; ++i)
        af[i] = *(const bfrag8*)&As[(wr + i * 16 + ln) * 64 + ((kk * 4 + lq) ^ swz) * 8];
#pragma unroll
      for (int j = 0; j < 4; ++j)
        bfr[j] = *(const bfrag8*)&Bs[(wc + j * 16 + ln) * 64 + ((kk * 4 + lq) ^ swz) * 8];
#pragma unroll
      for (int i = 0; i < 4; ++i)
#pragma unroll
        for (int j = 0; j < 4; ++j)
          acc[i][j] = __builtin_amdgcn_mfma_f32_16x16x32_bf16(af[i], bfr[j], acc[i][j], 0, 0, 0);
    }
    __syncthreads();
  }

  // Epilogue: C/D layout col=lane&15, row=(lane>>4)*4+reg  [m89-verified]
#pragma unroll
  for (int i = 0; i < 4; ++i)
#pragma unroll
    for (int j = 0; j < 4; ++j) {
      const long m = bm + wr + i * 16 + lq * 4;
      const long n = bn + wc + j * 16 + ln;
#pragma unroll
      for (int r = 0; r < 4; ++r)
        C[(m + r) * (long)ldc_ + n] = f2b(acc[i][j][r]);
    }
}

// ---- one 128^2 PV job: out = (1/lsum)*P.Vt^T (r0-proven core) ------------
__device__ __forceinline__ void pv_job(
    int tid, unsigned short* __restrict__ As, unsigned short* __restrict__ Bs,
    const unsigned short* __restrict__ P, const unsigned short* __restrict__ Vt,
    float* __restrict__ out, const float* __restrict__ lsum,
    long z, long bm, long bn) {
  const unsigned short* A = P  + z * (long)SLEN * SLEN;   // lda 2048
  const unsigned short* B = Vt + z * SLEN;                // ldb 8192
  float* C = out + z * (long)SLEN * HID;                  // ldc 1024
  const float* lz = lsum + z * SLEN;

  const int lane = tid & 63;
  const int wave = tid >> 6;
  const int wr   = (wave >> 1) * 64;
  const int wc   = (wave & 1) * 64;
  const int ln   = lane & 15;
  const int lq   = lane >> 4;
  const int swz  = ln & 7;

  facc4 acc[4][4] = {};

  const unsigned short* ap[4]; const unsigned short* bp[4];
  unsigned short* asd[4]; unsigned short* bsd[4];
#pragma unroll
  for (int j = 0; j < 4; ++j) {
    const int c   = j * 256 + tid;
    const int row = c >> 3;
    const int src = ((c & 7) ^ (row & 7)) * 8;
    ap[j]  = A + (bm + row) * 2048l + src;
    bp[j]  = B + (bn + row) * 8192l + src;
    asd[j] = &As[c * 8];
    bsd[j] = &Bs[c * 8];
  }

  for (int k0 = 0; k0 < 2048; k0 += 64) {
#pragma unroll
    for (int j = 0; j < 4; ++j) { gl_lds16(ap[j], asd[j]); ap[j] += 64; }
#pragma unroll
    for (int j = 0; j < 4; ++j) { gl_lds16(bp[j], bsd[j]); bp[j] += 64; }
    __syncthreads();

#pragma unroll
    for (int kk = 0; kk < 2; ++kk) {
      bfrag8 af[4], bfr[4];
#pragma unroll
      for (int i = 0; i < 4; ++i)
        af[i] = *(const bfrag8*)&As[(wr + i * 16 + ln) * 64 + ((kk * 4 + lq) ^ swz) * 8];
#pragma unroll
      for (int j = 0; j < 4; ++j)
        bfr[j] = *(const bfrag8*)&Bs[(wc + j * 16 + ln) * 64 + ((kk * 4 + lq) ^ swz) * 8];
#pragma unroll
      for (int i = 0; i < 4; ++i)
#pragma unroll
        for (int j = 0; j < 4; ++j)
          acc[i][j] = __builtin_amdgcn_mfma_f32_16x16x32_bf16(af[i], bfr[j], acc[i][j], 0, 0, 0);
    }
    __syncthreads();
  }

  float inv[16];
#pragma unroll
  for (int i = 0; i < 4; ++i)
#pragma unroll
    for (int r = 0; r < 4; ++r)
      inv[i * 4 + r] = 1.0f / lz[bm + wr + i * 16 + lq * 4 + r];
#pragma unroll
  for (int i = 0; i < 4; ++i)
#pragma unroll
    for (int j = 0; j < 4; ++j) {
      const long m = bm + wr + i * 16 + lq * 4;
      const long n = bn + wc + j * 16 + ln;
#pragma unroll
      for (int r = 0; r < 4; ++r)
        C[(m + r) * 1024l + n] = acc[i][j][r] * inv[i * 4 + r];
    }
}

// ================= 256x256 / BK=64 core — 8-phase (scores) ================
// Exactly as benched in the r3/r4 283/278-us compositions.
template <int NT>
__device__ __forceinline__ void core256(
    const unsigned short* __restrict__ A, const unsigned short* __restrict__ B,
    const int lda, const int ldb,
    unsigned short* __restrict__ As, unsigned short* __restrict__ Bs,
    facc4 (&acc)[8][4]) {
  const int tid  = threadIdx.x;          // 0..511
  const int lane = tid & 63;
  const int wave = tid >> 6;             // 0..7
  const int wm = wave >> 2;              // 0..1
  const int wn = wave & 3;               // 0..3
  const int ln = lane & 15;
  const int lq = lane >> 4;
  const int swz = ln & 7;

  const int row0 = tid >> 3;
  const int blk  = (tid & 7) ^ (row0 & 7);
  const unsigned short* pA = A + (long)row0 * lda + blk * 8;
  const unsigned short* pB = B + (long)row0 * ldb + blk * 8;
  const long a64 = 64l * lda, b64 = 64l * ldb;
  unsigned short* dA = As + tid * 8;
  unsigned short* dB = Bs + tid * 8;

#define STG_A(h, b, t) do { const unsigned short* g_ = pA + (h) * (a64 * 2) + (long)(t) * 64; \
    gl_lds16(g_,       dA + (b) * 16384 + (h) * 8192); \
    gl_lds16(g_ + a64, dA + (b) * 16384 + (h) * 8192 + 4096); } while (0)
#define STG_B(h, b, t) do { const unsigned short* g_ = pB + (h) * (b64 * 2) + (long)(t) * 64; \
    gl_lds16(g_,       dB + (b) * 16384 + (h) * 8192); \
    gl_lds16(g_ + b64, dB + (b) * 16384 + (h) * 8192 + 4096); } while (0)

  const int o0 = (lq ^ swz) * 8;
  const int o1 = ((4 + lq) ^ swz) * 8;
  const int aOfs = wm * 8192 + ln * 64;
  const int bOfs = (wn >> 1) * 8192 + ((wn & 1) * 64 + ln) * 64;

#define RD_A4(dst, bufb, mb) do { \
  _Pragma("unroll") for (int m_ = 0; m_ < 4; ++m_) { \
    dst[m_][0] = *(const bfrag8*)(As + (bufb) + aOfs + ((mb) + m_) * 1024 + o0); \
    dst[m_][1] = *(const bfrag8*)(As + (bufb) + aOfs + ((mb) + m_) * 1024 + o1); \
  } } while (0)
#define RD_B2(dst, bufb, nb) do { \
  _Pragma("unroll") for (int n_ = 0; n_ < 2; ++n_) { \
    dst[n_][0] = *(const bfrag8*)(Bs + (bufb) + bOfs + ((nb) + n_) * 1024 + o0); \
    dst[n_][1] = *(const bfrag8*)(Bs + (bufb) + bOfs + ((nb) + n_) * 1024 + o1); \
  } } while (0)

#define MFMAQ(AF, BF, MO, NO) do { \
  _Pragma("unroll") for (int m_ = 0; m_ < 4; ++m_) \
  _Pragma("unroll") for (int n_ = 0; n_ < 2; ++n_) { \
    acc[(MO)+m_][(NO)+n_] = __builtin_amdgcn_mfma_f32_16x16x32_bf16( \
        AF[m_][0], BF[n_][0], acc[(MO)+m_][(NO)+n_], 0, 0, 0); \
    acc[(MO)+m_][(NO)+n_] = __builtin_amdgcn_mfma_f32_16x16x32_bf16( \
        AF[m_][1], BF[n_][1], acc[(MO)+m_][(NO)+n_], 0, 0, 0); \
  } } while (0)

#define PH_MID \
  __builtin_amdgcn_s_barrier(); \
  asm volatile("s_waitcnt lgkmcnt(0)" ::: "memory"); \
  __builtin_amdgcn_sched_barrier(0); \
  __builtin_amdgcn_s_setprio(1)
#define PH_END \
  __builtin_amdgcn_s_setprio(0); \
  __builtin_amdgcn_sched_barrier(0); \
  __builtin_amdgcn_s_barrier()

  STG_A(0, 0, 0); STG_A(1, 0, 0); STG_B(0, 0, 0); STG_B(1, 0, 0);
  STG_B(0, 1, 1); STG_B(1, 1, 1);
  asm volatile("s_waitcnt vmcnt(4)" ::: "memory");
  __builtin_amdgcn_s_barrier();

  constexpr int NI = NT / 2;
#pragma unroll 1
  for (int i = 0; i < NI - 1; ++i) {
    const int O1 = 2 * i + 1, E2 = 2 * i + 2, O2 = 2 * i + 3;
    {
      bfrag8 a0[4][2], a1[4][2], b0[2][2], b1[2][2];
      RD_A4(a0, 0, 0); RD_B2(b0, 0, 0); STG_A(0, 1, O1);
      PH_MID; MFMAQ(a0, b0, 0, 0); PH_END;
      RD_B2(b1, 0, 2); STG_A(1, 1, O1);
      PH_MID; MFMAQ(a0, b1, 0, 2); PH_END;
      RD_A4(a1, 0, 4); STG_B(0, 0, E2);
      PH_MID; MFMAQ(a1, b1, 4, 2); PH_END;
      STG_B(1, 0, E2);
      PH_MID; MFMAQ(a1, b0, 4, 0);
      __builtin_amdgcn_s_setprio(0);
      __builtin_amdgcn_sched_barrier(0);
      asm volatile("s_waitcnt vmcnt(4)" ::: "memory");
      __builtin_amdgcn_s_barrier();
    }
    {
      bfrag8 a0[4][2], a1[4][2], b0[2][2], b1[2][2];
      RD_A4(a0, 16384, 0); RD_B2(b0, 16384, 0); STG_A(0, 0, E2);
      PH_MID; MFMAQ(a0, b0, 0, 0); PH_END;
      RD_B2(b1, 16384, 2); STG_A(1, 0, E2);
      PH_MID; MFMAQ(a0, b1, 0, 2); PH_END;
      RD_A4(a1, 16384, 4); STG_B(0, 1, O2);
      PH_MID; MFMAQ(a1, b1, 4, 2); PH_END;
      STG_B(1, 1, O2);
      PH_MID; MFMAQ(a1, b0, 4, 0);
      __builtin_amdgcn_s_setprio(0);
      __builtin_amdgcn_sched_barrier(0);
      asm volatile("s_waitcnt vmcnt(4)" ::: "memory");
      __builtin_amdgcn_s_barrier();
    }
  }
  {
    const int O1 = NT - 1;
    {
      bfrag8 a0[4][2], a1[4][2], b0[2][2], b1[2][2];
      RD_A4(a0, 0, 0); RD_B2(b0, 0, 0); STG_A(0, 1, O1);
      PH_MID; MFMAQ(a0, b0, 0, 0); PH_END;
      RD_B2(b1, 0, 2); STG_A(1, 1, O1);
      PH_MID; MFMAQ(a0, b1, 0, 2); PH_END;
      RD_A4(a1, 0, 4);
      PH_MID; MFMAQ(a1, b1, 4, 2); PH_END;
      PH_MID; MFMAQ(a1, b0, 4, 0);
      __builtin_amdgcn_s_setprio(0);
      __builtin_amdgcn_sched_barrier(0);
      asm volatile("s_waitcnt vmcnt(0)" ::: "memory");
      __builtin_amdgcn_s_barrier();
    }
    {
      bfrag8 a0[4][2], a1[4][2], b0[2][2], b1[2][2];
      RD_A4(a0, 16384, 0); RD_B2(b0, 16384, 0);
      PH_MID; MFMAQ(a0, b0, 0, 0); PH_END;
      RD_B2(b1, 16384, 2);
      PH_MID; MFMAQ(a0, b1, 0, 2); PH_END;
      RD_A4(a1, 16384, 4);
      PH_MID; MFMAQ(a1, b1, 4, 2); PH_END;
      PH_MID; MFMAQ(a1, b0, 4, 0);
      __builtin_amdgcn_s_setprio(0);
    }
  }
#undef PH_MID
#undef PH_END
#undef MFMAQ
#undef RD_A4
#undef RD_B2
#undef STG_A
#undef STG_B
}

// ---- one 256^2 scores job: P = exp(Q.K^T/32) bf16, lsum += row sums ------
__device__ __forceinline__ void scores_job(
    unsigned short* __restrict__ smem,
    const unsigned short* __restrict__ Qb, const unsigned short* __restrict__ Kb,
    unsigned short* __restrict__ P, float* __restrict__ lsum,
    long z, long bm, long bn) {
  unsigned short* As = smem;
  unsigned short* Bs = smem + 32768;
  const long SH = (long)SLEN * HID, SS = (long)SLEN * SLEN;
  facc4 acc[8][4] = {};
  core256<HID / 64>(Qb + z * SH + bm * 1024, Kb + z * SH + bn * 1024, 1024, 1024,
                    As, Bs, acc);

  unsigned short* Pz = P + z * SS;
  float* lz = lsum + z * SLEN;
  const int lane = threadIdx.x & 63, wave = threadIdx.x >> 6;
  const int wm = wave >> 2, wn = wave & 3;
  const int ln = lane & 15, lq = lane >> 4;
#pragma unroll
  for (int m = 0; m < 8; ++m) {
#pragma unroll
    for (int r = 0; r < 4; ++r) {
      const long qrow = bm + wm * 128 + m * 16 + lq * 4 + r;
      float rowsum = 0.f;
#pragma unroll
      for (int n = 0; n < 4; ++n) {
        const long kcol = bn + wn * 64 + n * 16 + ln;
        float e = __expf(acc[m][n][r] * 0.03125f);
        Pz[qrow * (long)SLEN + kcol] = f2b(e);
        rowsum += e;
      }
      rowsum += __shfl_xor(rowsum, 1, 64);
      rowsum += __shfl_xor(rowsum, 2, 64);
      rowsum += __shfl_xor(rowsum, 4, 64);
      rowsum += __shfl_xor(rowsum, 8, 64);
      if (ln == 0) atomicAdd(&lz[qrow], rowsum);
    }
  }
}

// ==================== THE fused cooperative mega-kernel ====================
// Theory under test: ~100 us of the 278-us graph is inter-dispatch overhead
// (constant gap between sum-of-dispatch-durs ~175 us and graph time across
// all 5 rounds). One kernel + 3 grid.sync()s replaces 4 dispatch nodes.
// Phase 2/4 run two independent 256-thread half-units per block (shared
// __syncthreads, identical barrier counts) — reproducing r0's measured
// 8-waves/CU proj concurrency at 1 block/CU.
__global__ __launch_bounds__(512, 2) void fused_all(
    const float* __restrict__ q_in, const float* __restrict__ k_in,
    const float* __restrict__ v_in, const float* __restrict__ wq,
    const float* __restrict__ wk, const float* __restrict__ wv,
    float* __restrict__ out, unsigned short* __restrict__ ws) {
  extern __shared__ unsigned short smem[];   // 128 KiB

  const long NXH = (long)BATCH * SLEN * HID;   // 8,388,608
  const long NW  = (long)HID * HID;            // 1,048,576
  unsigned short* Xq  = ws;
  unsigned short* Xk  = Xq  + NXH;
  unsigned short* Xv  = Xk  + NXH;
  unsigned short* Wqb = Xv  + NXH;
  unsigned short* Wkb = Wqb + NW;
  unsigned short* Wvb = Wkb + NW;
  unsigned short* Qb  = Wvb + NW;
  unsigned short* Kb  = Qb  + NXH;
  unsigned short* Vt  = Kb  + NXH;             // ld 8192
  float*          lsum = (float*)(Vt + NXH);
  unsigned short* P   = Xq;                    // aliases Xq+Xk (dead by ph3)

  cg::grid_group grid = cg::this_grid();

  // ---- phase 1: cast all six inputs + zero lsum (BW-bound) ----
  {
    const long gid = (long)blockIdx.x * 512 + threadIdx.x;   // 0..131071
    if (gid < 2048) {
      float4 z4 = {0.f, 0.f, 0.f, 0.f};
      ((float4*)lsum)[gid] = z4;
    }
    us4* dst = (us4*)ws;
    const long TOT = 7077888;   // 28,311,552 elems / 4
#pragma unroll 1
    for (long i = gid; i < TOT; i += 131072)
      cast_elem(i, q_in, k_in, v_in, wq, wk, wv, dst);
  }
  grid.sync();

  // ---- phase 2: QKV projections, 6 jobs/block (2 halves x 3 seq) ----
  {
    const int half = threadIdx.x >> 8;           // 0,1
    const int tid  = threadIdx.x & 255;
    unsigned short* As = smem + half * 16384;    // 32 KiB per half
    unsigned short* Bs = As + 8192;
    const int base = (blockIdx.x & 7) * 192 + (blockIdx.x >> 3) * 6 + half * 3;
#pragma unroll 1
    for (int j = 0; j < 3; ++j)
      proj_job(base + j, tid, As, Bs, Xq, Wqb, Xk, Wkb, Xv, Wvb, Qb, Kb, Vt);
  }
  grid.sync();

  // ---- phase 3: scores (8-phase 256^2 core), 1 job/block ----
  {
    const long z  = blockIdx.x >> 6;
    const int pid = blockIdx.x & 63;
    const int p2  = (pid & 7) * 8 + (pid >> 3);  // XCD gets one bm row-panel
    const long bm = (long)(p2 >> 3) * 256;
    const long bn = (long)(p2 & 7) * 256;
    scores_job(smem, Qb, Kb, P, lsum, z, bm, bn);
  }
  grid.sync();

  // ---- phase 4: PV, 2 jobs/block (1 per half) ----
  {
    const int half = threadIdx.x >> 8;
    const int tid  = threadIdx.x & 255;
    unsigned short* As = smem + half * 16384;
    unsigned short* Bs = As + 8192;
    const int unit   = (blockIdx.x >> 3) * 2 + half;   // 0..63 within XCD
    const int jobidx = (blockIdx.x & 7) * 64 + unit;   // 0..511, XCD-contiguous
    const long z = jobidx >> 7;                        // 128 jobs/batch
    const int within = jobidx & 63;
    const long bm = (long)(((jobidx >> 6) & 1) * 8 +
                           (within >> 5) * 4 + (within & 3)) * 128;
    const long bn = (long)((within >> 2) & 7) * 128;
    pv_job(tid, As, Bs, P, Vt, out, lsum, z, bm, bn);
  }
}

// ==================== fallback kernels (exact r4 pipeline) =================
__global__ __launch_bounds__(256) void cast_all(
    const float* __restrict__ q, const float* __restrict__ k,
    const float* __restrict__ v, const float* __restrict__ wq,
    const float* __restrict__ wk, const float* __restrict__ wv,
    us4* __restrict__ dst, float* __restrict__ lsum) {
  if (blockIdx.x < 8) {
    float4 z = {0.f, 0.f, 0.f, 0.f};
    ((float4*)lsum)[blockIdx.x * 256 + threadIdx.x] = z;
  }
  const long i = (long)blockIdx.x * 256 + threadIdx.x;
  cast_elem(i, q, k, v, wq, wk, wv, dst);
}

__global__ __launch_bounds__(256) void proj3(
    const unsigned short* __restrict__ Xq, const unsigned short* __restrict__ Wqb,
    const unsigned short* __restrict__ Xk, const unsigned short* __restrict__ Wkb,
    const unsigned short* __restrict__ Xv, const unsigned short* __restrict__ Wvb,
    unsigned short* __restrict__ Qb, unsigned short* __restrict__ Kb,
    unsigned short* __restrict__ Vt) {
  __shared__ __align__(16) unsigned short As[128 * 64];
  __shared__ __align__(16) unsigned short Bs[128 * 64];
  const int p2 = (blockIdx.x & 7) * 192 + (blockIdx.x >> 3);
  proj_job(p2, threadIdx.x, As, Bs, Xq, Wqb, Xk, Wkb, Xv, Wvb, Qb, Kb, Vt);
}

__global__ __launch_bounds__(512, 2) void scores256(
    const unsigned short* __restrict__ Q, const unsigned short* __restrict__ Kb,
    unsigned short* __restrict__ P, float* __restrict__ lsum) {
  extern __shared__ unsigned short smem[];
  const long z = blockIdx.z;
  const int pid = blockIdx.y * 8 + blockIdx.x;
  const int p2  = (pid & 7) * 8 + (pid >> 3);
  scores_job(smem, Q, Kb, P, lsum, z, (long)(p2 >> 3) * 256, (long)(p2 & 7) * 256);
}

__global__ __launch_bounds__(256) void pv128(
    const unsigned short* __restrict__ P, const unsigned short* __restrict__ Vt,
    float* __restrict__ out, const float* __restrict__ lsum) {
  __shared__ __align__(16) unsigned short As[128 * 64];
  __shared__ __align__(16) unsigned short Bs[128 * 64];
  const int pid = blockIdx.y * 16 + blockIdx.x;    // grid (16,8,B)
  const int p2  = (pid & 7) * 16 + (pid >> 3);
  const int gid = p2 >> 5, rem = p2 & 31;
  const long bm = (long)(gid * 4 + (rem & 3)) * 128;
  const long bn = (long)(rem >> 2) * 128;
  pv_job(threadIdx.x, As, Bs, P, Vt, out, lsum, (long)blockIdx.z, bm, bn);
}

extern "C" void kernel_launch(void* const* d_in, const int* in_sizes, int n_in,
                              void* d_out, int out_size, void* d_ws, size_t ws_size,
                              hipStream_t stream) {
  const float* q_in = (const float*)d_in[0];
  const float* k_in = (const float*)d_in[1];
  const float* v_in = (const float*)d_in[2];
  const float* wq   = (const float*)d_in[3];
  const float* wk   = (const float*)d_in[4];
  const float* wv   = (const float*)d_in[5];
  float* out = (float*)d_out;
  unsigned short* ws = (unsigned short*)d_ws;

  const long NXH = (long)BATCH * SLEN * HID;
  const long NW  = (long)HID * HID;

  static bool attr_done = false;
  if (!attr_done) {
    hipFuncSetAttribute(reinterpret_cast<const void*>(fused_all),
                        hipFuncAttributeMaxDynamicSharedMemorySize, 131072);
    hipFuncSetAttribute(reinterpret_cast<const void*>(scores256),
                        hipFuncAttributeMaxDynamicSharedMemorySize, 131072);
    attr_done = true;
  }

  void* params[] = {(void*)&q_in, (void*)&k_in, (void*)&v_in,
                    (void*)&wq,   (void*)&wk,   (void*)&wv,
                    (void*)&out,  (void*)&ws};
  hipError_t ce = hipLaunchCooperativeKernel(
      reinterpret_cast<const void*>(fused_all), dim3(256), dim3(512),
      params, 131072, stream);
  if (ce != hipSuccess) {
    (void)hipGetLastError();   // clear sticky error; fall back to 4-dispatch
    unsigned short* Xq  = ws;
    unsigned short* Xk  = Xq  + NXH;
    unsigned short* Xv  = Xk  + NXH;
    unsigned short* Wqb = Xv  + NXH;
    unsigned short* Wkb = Wqb + NW;
    unsigned short* Wvb = Wkb + NW;
    unsigned short* Qb  = Wvb + NW;
    unsigned short* Kb  = Qb  + NXH;
    unsigned short* Vt  = Kb  + NXH;
    float*          lsum = (float*)(Vt + NXH);
    unsigned short* P   = Xq;

    cast_all<<<dim3(27648), dim3(256), 0, stream>>>(q_in, k_in, v_in, wq, wk, wv,
                                                    (us4*)ws, lsum);
    proj3<<<dim3(1536), dim3(256), 0, stream>>>(Xq, Wqb, Xk, Wkb, Xv, Wvb,
                                                Qb, Kb, Vt);
    scores256<<<dim3(8, 8, BATCH), dim3(512), 131072, stream>>>(Qb, Kb, P, lsum);
    pv128<<<dim3(16, 8, BATCH), dim3(256), 0, stream>>>(P, Vt, out, lsum);
  }
}

// Round 6
// 280.609 us; speedup vs baseline: 1.6158x; 1.6158x over previous
//
#include <hip/hip_runtime.h>
#include <hip/hip_bf16.h>
#include <stdint.h>

// Problem constants: B=4, S=2048, H=1024
#define BATCH 4
#define SLEN  2048
#define HID   1024

typedef __attribute__((ext_vector_type(8))) short bfrag8;   // 8 bf16 (4 VGPRs)
typedef __attribute__((ext_vector_type(4))) float facc4;    // 4 fp32 acc
typedef __attribute__((ext_vector_type(4))) unsigned short us4;

__device__ __forceinline__ unsigned short f2b(float f) {
  union { float f; unsigned int i; } x; x.f = f;
  unsigned int r = x.i + 0x7FFFu + ((x.i >> 16) & 1u);  // RNE
  return (unsigned short)(r >> 16);
}

__device__ __forceinline__ void gl_lds16(const void* g, void* l) {
  __builtin_amdgcn_global_load_lds(
      (const __attribute__((address_space(1))) void*)g,
      (__attribute__((address_space(3))) void*)l, 16, 0, 0);
}

// ------------- fused fp32 -> bf16 cast of all six inputs + lsum zero -------
// At BW ceiling: 170 MB / ~27 us = 6.3 TB/s.
__global__ __launch_bounds__(256) void cast_all(
    const float* __restrict__ q, const float* __restrict__ k,
    const float* __restrict__ v, const float* __restrict__ wq,
    const float* __restrict__ wk, const float* __restrict__ wv,
    us4* __restrict__ dst, float* __restrict__ lsum) {
  if (blockIdx.x < 8) {
    float4 z = {0.f, 0.f, 0.f, 0.f};
    ((float4*)lsum)[blockIdx.x * 256 + threadIdx.x] = z;
  }
  const long i = (long)blockIdx.x * 256 + threadIdx.x;
  const long S1 = 2097152, S2 = 4194304, S3 = 6291456,
             S4 = 6553600, S5 = 6815744;
  const float4* src; long off;
  if (i < S2) {
    if (i < S1) { src = (const float4*)q;  off = i; }
    else        { src = (const float4*)k;  off = i - S1; }
  } else if (i < S3) { src = (const float4*)v;  off = i - S2; }
  else if   (i < S4) { src = (const float4*)wq; off = i - S3; }
  else if   (i < S5) { src = (const float4*)wk; off = i - S4; }
  else               { src = (const float4*)wv; off = i - S5; }
  float4 x = src[off];
  us4 o;
  o.x = f2b(x.x); o.y = f2b(x.y); o.z = f2b(x.z); o.w = f2b(x.w);
  dst[i] = o;
}

// ============ fused QKV projection: r0-proven 128^2 core (912 TF) =========
// r5 post-mortem: 1536 small blocks with 2-3/CU cross-block overlap remains
// the best proj structure measured this session (56.7-59.6 us, MfmaUtil 37%).
__global__ __launch_bounds__(256) void proj3(
    const unsigned short* __restrict__ Xq, const unsigned short* __restrict__ Wqb,
    const unsigned short* __restrict__ Xk, const unsigned short* __restrict__ Wkb,
    const unsigned short* __restrict__ Xv, const unsigned short* __restrict__ Wvb,
    unsigned short* __restrict__ Qb, unsigned short* __restrict__ Kb,
    unsigned short* __restrict__ Vt) {
  const int pid = blockIdx.x;
  const int p2     = (pid & 7) * 192 + (pid >> 3);  // XCD-contiguous
  const int g      = p2 >> 9;                       // 0:Q 1:K 2:Vt
  const int within = p2 & 511;

  const unsigned short* A; const unsigned short* B; unsigned short* C;
  long bm, bn; int ldc_;
  if (g == 0)      { A = Xq; B = Wqb; C = Qb; }
  else if (g == 1) { A = Xk; B = Wkb; C = Kb; }
  else             { A = Wvb; B = Xv; C = Vt; }
  if (g < 2) {   // nbm=64, nbn=8, GROUP=4
    const int gid = within >> 5, rem = within & 31;
    bm = (long)(gid * 4 + (rem & 3)) * 128;
    bn = (long)(rem >> 2) * 128;
    ldc_ = 1024;
  } else {       // nbm=8, nbn=64, GROUP=4
    const int gid = within >> 8, rem = within & 255;
    bm = (long)(gid * 4 + (rem & 3)) * 128;
    bn = (long)(rem >> 2) * 128;
    ldc_ = 8192;
  }

  __shared__ __align__(16) unsigned short As[128 * 64];
  __shared__ __align__(16) unsigned short Bs[128 * 64];

  const int tid  = threadIdx.x;
  const int lane = tid & 63;
  const int wave = tid >> 6;
  const int wr   = (wave >> 1) * 64;
  const int wc   = (wave & 1) * 64;
  const int ln   = lane & 15;
  const int lq   = lane >> 4;
  const int swz  = ln & 7;

  facc4 acc[4][4] = {};

  const unsigned short* ap[4]; const unsigned short* bp[4];
  unsigned short* asd[4]; unsigned short* bsd[4];
#pragma unroll
  for (int j = 0; j < 4; ++j) {
    const int c   = j * 256 + tid;
    const int row = c >> 3;
    const int src = ((c & 7) ^ (row & 7)) * 8;
    ap[j]  = A + (bm + row) * 1024 + src;
    bp[j]  = B + (bn + row) * 1024 + src;
    asd[j] = &As[c * 8];
    bsd[j] = &Bs[c * 8];
  }

  for (int k0 = 0; k0 < 1024; k0 += 64) {
#pragma unroll
    for (int j = 0; j < 4; ++j) { gl_lds16(ap[j], asd[j]); ap[j] += 64; }
#pragma unroll
    for (int j = 0; j < 4; ++j) { gl_lds16(bp[j], bsd[j]); bp[j] += 64; }
    __syncthreads();

#pragma unroll
    for (int kk = 0; kk < 2; ++kk) {
      bfrag8 af[4], bfr[4];
#pragma unroll
      for (int i = 0; i < 4; ++i)
        af[i] = *(const bfrag8*)&As[(wr + i * 16 + ln) * 64 + ((kk * 4 + lq) ^ swz) * 8];
#pragma unroll
      for (int j = 0; j < 4; ++j)
        bfr[j] = *(const bfrag8*)&Bs[(wc + j * 16 + ln) * 64 + ((kk * 4 + lq) ^ swz) * 8];
#pragma unroll
      for (int i = 0; i < 4; ++i)
#pragma unroll
        for (int j = 0; j < 4; ++j)
          acc[i][j] = __builtin_amdgcn_mfma_f32_16x16x32_bf16(af[i], bfr[j], acc[i][j], 0, 0, 0);
    }
    __syncthreads();
  }

  // Epilogue: C/D layout col=lane&15, row=(lane>>4)*4+reg  [m89-verified]
#pragma unroll
  for (int i = 0; i < 4; ++i)
#pragma unroll
    for (int j = 0; j < 4; ++j) {
      const long m = bm + wr + i * 16 + lq * 4;
      const long n = bn + wc + j * 16 + ln;
#pragma unroll
      for (int r = 0; r < 4; ++r)
        C[(m + r) * (long)ldc_ + n] = f2b(acc[i][j][r]);
    }
}

// ================= 256x256 / BK=64 core — 8-phase (scores) ================
// Exactly as benched in the r3/r4 283/278-us compositions.
template <int NT>
__device__ __forceinline__ void core256(
    const unsigned short* __restrict__ A, const unsigned short* __restrict__ B,
    const int lda, const int ldb,
    unsigned short* __restrict__ As, unsigned short* __restrict__ Bs,
    facc4 (&acc)[8][4]) {
  const int tid  = threadIdx.x;          // 0..511
  const int lane = tid & 63;
  const int wave = tid >> 6;             // 0..7
  const int wm = wave >> 2;              // 0..1
  const int wn = wave & 3;               // 0..3
  const int ln = lane & 15;
  const int lq = lane >> 4;
  const int swz = ln & 7;

  const int row0 = tid >> 3;
  const int blk  = (tid & 7) ^ (row0 & 7);
  const unsigned short* pA = A + (long)row0 * lda + blk * 8;
  const unsigned short* pB = B + (long)row0 * ldb + blk * 8;
  const long a64 = 64l * lda, b64 = 64l * ldb;
  unsigned short* dA = As + tid * 8;
  unsigned short* dB = Bs + tid * 8;

#define STG_A(h, b, t) do { const unsigned short* g_ = pA + (h) * (a64 * 2) + (long)(t) * 64; \
    gl_lds16(g_,       dA + (b) * 16384 + (h) * 8192); \
    gl_lds16(g_ + a64, dA + (b) * 16384 + (h) * 8192 + 4096); } while (0)
#define STG_B(h, b, t) do { const unsigned short* g_ = pB + (h) * (b64 * 2) + (long)(t) * 64; \
    gl_lds16(g_,       dB + (b) * 16384 + (h) * 8192); \
    gl_lds16(g_ + b64, dB + (b) * 16384 + (h) * 8192 + 4096); } while (0)

  const int o0 = (lq ^ swz) * 8;
  const int o1 = ((4 + lq) ^ swz) * 8;
  const int aOfs = wm * 8192 + ln * 64;
  const int bOfs = (wn >> 1) * 8192 + ((wn & 1) * 64 + ln) * 64;

#define RD_A4(dst, bufb, mb) do { \
  _Pragma("unroll") for (int m_ = 0; m_ < 4; ++m_) { \
    dst[m_][0] = *(const bfrag8*)(As + (bufb) + aOfs + ((mb) + m_) * 1024 + o0); \
    dst[m_][1] = *(const bfrag8*)(As + (bufb) + aOfs + ((mb) + m_) * 1024 + o1); \
  } } while (0)
#define RD_B2(dst, bufb, nb) do { \
  _Pragma("unroll") for (int n_ = 0; n_ < 2; ++n_) { \
    dst[n_][0] = *(const bfrag8*)(Bs + (bufb) + bOfs + ((nb) + n_) * 1024 + o0); \
    dst[n_][1] = *(const bfrag8*)(Bs + (bufb) + bOfs + ((nb) + n_) * 1024 + o1); \
  } } while (0)

#define MFMAQ(AF, BF, MO, NO) do { \
  _Pragma("unroll") for (int m_ = 0; m_ < 4; ++m_) \
  _Pragma("unroll") for (int n_ = 0; n_ < 2; ++n_) { \
    acc[(MO)+m_][(NO)+n_] = __builtin_amdgcn_mfma_f32_16x16x32_bf16( \
        AF[m_][0], BF[n_][0], acc[(MO)+m_][(NO)+n_], 0, 0, 0); \
    acc[(MO)+m_][(NO)+n_] = __builtin_amdgcn_mfma_f32_16x16x32_bf16( \
        AF[m_][1], BF[n_][1], acc[(MO)+m_][(NO)+n_], 0, 0, 0); \
  } } while (0)

#define PH_MID \
  __builtin_amdgcn_s_barrier(); \
  asm volatile("s_waitcnt lgkmcnt(0)" ::: "memory"); \
  __builtin_amdgcn_sched_barrier(0); \
  __builtin_amdgcn_s_setprio(1)
#define PH_END \
  __builtin_amdgcn_s_setprio(0); \
  __builtin_amdgcn_sched_barrier(0); \
  __builtin_amdgcn_s_barrier()

  STG_A(0, 0, 0); STG_A(1, 0, 0); STG_B(0, 0, 0); STG_B(1, 0, 0);
  STG_B(0, 1, 1); STG_B(1, 1, 1);
  asm volatile("s_waitcnt vmcnt(4)" ::: "memory");
  __builtin_amdgcn_s_barrier();

  constexpr int NI = NT / 2;
#pragma unroll 1
  for (int i = 0; i < NI - 1; ++i) {
    const int O1 = 2 * i + 1, E2 = 2 * i + 2, O2 = 2 * i + 3;
    {
      bfrag8 a0[4][2], a1[4][2], b0[2][2], b1[2][2];
      RD_A4(a0, 0, 0); RD_B2(b0, 0, 0); STG_A(0, 1, O1);
      PH_MID; MFMAQ(a0, b0, 0, 0); PH_END;
      RD_B2(b1, 0, 2); STG_A(1, 1, O1);
      PH_MID; MFMAQ(a0, b1, 0, 2); PH_END;
      RD_A4(a1, 0, 4); STG_B(0, 0, E2);
      PH_MID; MFMAQ(a1, b1, 4, 2); PH_END;
      STG_B(1, 0, E2);
      PH_MID; MFMAQ(a1, b0, 4, 0);
      __builtin_amdgcn_s_setprio(0);
      __builtin_amdgcn_sched_barrier(0);
      asm volatile("s_waitcnt vmcnt(4)" ::: "memory");
      __builtin_amdgcn_s_barrier();
    }
    {
      bfrag8 a0[4][2], a1[4][2], b0[2][2], b1[2][2];
      RD_A4(a0, 16384, 0); RD_B2(b0, 16384, 0); STG_A(0, 0, E2);
      PH_MID; MFMAQ(a0, b0, 0, 0); PH_END;
      RD_B2(b1, 16384, 2); STG_A(1, 0, E2);
      PH_MID; MFMAQ(a0, b1, 0, 2); PH_END;
      RD_A4(a1, 16384, 4); STG_B(0, 1, O2);
      PH_MID; MFMAQ(a1, b1, 4, 2); PH_END;
      STG_B(1, 1, O2);
      PH_MID; MFMAQ(a1, b0, 4, 0);
      __builtin_amdgcn_s_setprio(0);
      __builtin_amdgcn_sched_barrier(0);
      asm volatile("s_waitcnt vmcnt(4)" ::: "memory");
      __builtin_amdgcn_s_barrier();
    }
  }
  {
    const int O1 = NT - 1;
    {
      bfrag8 a0[4][2], a1[4][2], b0[2][2], b1[2][2];
      RD_A4(a0, 0, 0); RD_B2(b0, 0, 0); STG_A(0, 1, O1);
      PH_MID; MFMAQ(a0, b0, 0, 0); PH_END;
      RD_B2(b1, 0, 2); STG_A(1, 1, O1);
      PH_MID; MFMAQ(a0, b1, 0, 2); PH_END;
      RD_A4(a1, 0, 4);
      PH_MID; MFMAQ(a1, b1, 4, 2); PH_END;
      PH_MID; MFMAQ(a1, b0, 4, 0);
      __builtin_amdgcn_s_setprio(0);
      __builtin_amdgcn_sched_barrier(0);
      asm volatile("s_waitcnt vmcnt(0)" ::: "memory");
      __builtin_amdgcn_s_barrier();
    }
    {
      bfrag8 a0[4][2], a1[4][2], b0[2][2], b1[2][2];
      RD_A4(a0, 16384, 0); RD_B2(b0, 16384, 0);
      PH_MID; MFMAQ(a0, b0, 0, 0); PH_END;
      RD_B2(b1, 16384, 2);
      PH_MID; MFMAQ(a0, b1, 0, 2); PH_END;
      RD_A4(a1, 16384, 4);
      PH_MID; MFMAQ(a1, b1, 4, 2); PH_END;
      PH_MID; MFMAQ(a1, b0, 4, 0);
      __builtin_amdgcn_s_setprio(0);
    }
  }
#undef PH_MID
#undef PH_END
#undef MFMAQ
#undef RD_A4
#undef RD_B2
#undef STG_A
#undef STG_B
}

// ============ scores on the 256^2 core: P = exp(Q.K^T/32), lsum += ========
// 256 blocks total (8x8 tiles x 4 batches) = exactly 1 per CU.
__global__ __launch_bounds__(512, 2) void scores256(
    const unsigned short* __restrict__ Q, const unsigned short* __restrict__ Kb,
    unsigned short* __restrict__ P, float* __restrict__ lsum) {
  extern __shared__ unsigned short smem[];
  unsigned short* As = smem;
  unsigned short* Bs = smem + 32768;

  const long z = blockIdx.z;
  const int pid = blockIdx.y * 8 + blockIdx.x;
  const int p2  = (pid & 7) * 8 + (pid >> 3);   // XCD gets one bm row-panel
  const long bm = (long)(p2 >> 3) * 256;
  const long bn = (long)(p2 & 7) * 256;

  const long SH = (long)SLEN * HID, SS = (long)SLEN * SLEN;
  facc4 acc[8][4] = {};
  core256<HID / 64>(Q + z * SH + bm * 1024, Kb + z * SH + bn * 1024, 1024, 1024,
                    As, Bs, acc);

  unsigned short* Pz = P + z * SS;
  float* lz = lsum + z * SLEN;
  const int lane = threadIdx.x & 63, wave = threadIdx.x >> 6;
  const int wm = wave >> 2, wn = wave & 3;
  const int ln = lane & 15, lq = lane >> 4;
#pragma unroll
  for (int m = 0; m < 8; ++m) {
#pragma unroll
    for (int r = 0; r < 4; ++r) {
      const long q = bm + wm * 128 + m * 16 + lq * 4 + r;
      float rowsum = 0.f;
#pragma unroll
      for (int n = 0; n < 4; ++n) {
        const long kcol = bn + wn * 64 + n * 16 + ln;
        float e = __expf(acc[m][n][r] * 0.03125f);
        Pz[q * (long)SLEN + kcol] = f2b(e);
        rowsum += e;
      }
      rowsum += __shfl_xor(rowsum, 1, 64);
      rowsum += __shfl_xor(rowsum, 2, 64);
      rowsum += __shfl_xor(rowsum, 4, 64);
      rowsum += __shfl_xor(rowsum, 8, 64);
      if (ln == 0) atomicAdd(&lz[q], rowsum);
    }
  }
}

// ============ PV on a 256x128-tile 8-phase core: exact 1/CU packing ========
// out[b][q][h] = (1/lsum[b,q]) * sum_k P[b,q,k] * Vt[h][b*S+k]
// NEW this round: 8x8x4 = 256 blocks (1/CU, zero tail) — the regime where
// the 8-phase core proved itself (scores256). Wave grid 4M x 2N (64x64 per
// wave) for best LDS/MFMA balance (16 ds_read_b128/wave/K-tile).
// Stage slots per tile: A = 2 halves, B = 1 half (6 loads); counted
// vmcnt(2) at ph4/ph8 (8 outstanding, retire 6, keep 2); prologue 8 loads
// + vmcnt(2); peeled last iter stages A(O) at ph1/ph2, drains vmcnt(0) at
// ph4. Slot-free/landing deadlines hand-verified (same method as r3).
__global__ __launch_bounds__(512, 2) void pv256(
    const unsigned short* __restrict__ P, const unsigned short* __restrict__ Vt,
    float* __restrict__ out, const float* __restrict__ lsum) {
  extern __shared__ unsigned short smem[];   // 96 KiB
  unsigned short* As = smem;                 // 2 x 16384 shorts (256x64 ea)
  unsigned short* Bs = smem + 32768;         // 2 x 8192 shorts (128x64 ea)

  const long z  = blockIdx.z;
  const int pid = blockIdx.y * 8 + blockIdx.x;
  const int p2  = (pid & 7) * 8 + (pid >> 3);   // XCD-contiguous
  const long bm = (long)(p2 >> 3) * 256;        // 0..1792, q-rows
  const long bn = (long)(p2 & 7) * 128;         // 0..896,  h-cols

  const unsigned short* A = P  + z * (long)SLEN * SLEN + bm * 2048;  // lda 2048
  const unsigned short* B = Vt + z * SLEN + bn * 8192;               // ldb 8192
  float* C = out + z * (long)SLEN * HID;
  const float* lz = lsum + z * SLEN;

  const int tid  = threadIdx.x;
  const int lane = tid & 63;
  const int wave = tid >> 6;   // 0..7
  const int wm = wave >> 1;    // 0..3  (64 q-rows each)
  const int wn = wave & 1;     // 0..1  (64 h-cols each)
  const int ln = lane & 15;
  const int lq = lane >> 4;
  const int swz = ln & 7;

  const int row0 = tid >> 3;                 // 0..63
  const int blk  = (tid & 7) ^ (row0 & 7);   // pre-swizzled source block
  const unsigned short* pA = A + (long)row0 * 2048 + blk * 8;
  const unsigned short* pB = B + (long)row0 * 8192 + blk * 8;
  const long a64 = 64l * 2048, b64 = 64l * 8192;
  unsigned short* dA = As + tid * 8;
  unsigned short* dB = Bs + tid * 8;

#define PSTG_A(h, b, t) do { const unsigned short* g_ = pA + (h) * (a64 * 2) + (long)(t) * 64; \
    gl_lds16(g_,       dA + (b) * 16384 + (h) * 8192); \
    gl_lds16(g_ + a64, dA + (b) * 16384 + (h) * 8192 + 4096); } while (0)
#define PSTG_B(b, t) do { const unsigned short* g_ = pB + (long)(t) * 64; \
    gl_lds16(g_,       dB + (b) * 8192); \
    gl_lds16(g_ + b64, dB + (b) * 8192 + 4096); } while (0)

  const int o0 = (lq ^ swz) * 8;
  const int o1 = ((4 + lq) ^ swz) * 8;
  const int aOfs = wm * 4096 + ln * 64;   // row = wm*64 + m*16 + ln
  const int bOfs = wn * 4096 + ln * 64;   // row = wn*64 + n*16 + ln

#define PRD_A(dst, bufb, mb) do { \
  _Pragma("unroll") for (int m_ = 0; m_ < 2; ++m_) { \
    dst[m_][0] = *(const bfrag8*)(As + (bufb) + aOfs + ((mb) + m_) * 1024 + o0); \
    dst[m_][1] = *(const bfrag8*)(As + (bufb) + aOfs + ((mb) + m_) * 1024 + o1); \
  } } while (0)
#define PRD_B(dst, bufb, nb) do { \
  _Pragma("unroll") for (int n_ = 0; n_ < 2; ++n_) { \
    dst[n_][0] = *(const bfrag8*)(Bs + (bufb) + bOfs + ((nb) + n_) * 1024 + o0); \
    dst[n_][1] = *(const bfrag8*)(Bs + (bufb) + bOfs + ((nb) + n_) * 1024 + o1); \
  } } while (0)

  facc4 acc[4][4] = {};
#define PMFMAQ(AF, BF, MO, NO) do { \
  _Pragma("unroll") for (int m_ = 0; m_ < 2; ++m_) \
  _Pragma("unroll") for (int n_ = 0; n_ < 2; ++n_) { \
    acc[(MO)+m_][(NO)+n_] = __builtin_amdgcn_mfma_f32_16x16x32_bf16( \
        AF[m_][0], BF[n_][0], acc[(MO)+m_][(NO)+n_], 0, 0, 0); \
    acc[(MO)+m_][(NO)+n_] = __builtin_amdgcn_mfma_f32_16x16x32_bf16( \
        AF[m_][1], BF[n_][1], acc[(MO)+m_][(NO)+n_], 0, 0, 0); \
  } } while (0)

#define PH_MID \
  __builtin_amdgcn_s_barrier(); \
  asm volatile("s_waitcnt lgkmcnt(0)" ::: "memory"); \
  __builtin_amdgcn_sched_barrier(0); \
  __builtin_amdgcn_s_setprio(1)
#define PH_END \
  __builtin_amdgcn_s_setprio(0); \
  __builtin_amdgcn_sched_barrier(0); \
  __builtin_amdgcn_s_barrier()

  // prologue: tile0 full (A0,A1,B = 6 loads) -> buf0; B(1) -> buf1 (2 loads)
  PSTG_A(0, 0, 0); PSTG_A(1, 0, 0); PSTG_B(0, 0);
  PSTG_B(1, 1);
  asm volatile("s_waitcnt vmcnt(2)" ::: "memory");   // tile0 landed
  __builtin_amdgcn_s_barrier();

  constexpr int NT = 32;            // K = 2048 / BK=64
#pragma unroll 1
  for (int i = 0; i < NT / 2 - 1; ++i) {
    const int O1 = 2 * i + 1, E2 = 2 * i + 2, O2 = 2 * i + 3;
    {   // tile E (buf0)
      bfrag8 a0[2][2], a1[2][2], b0[2][2], b1[2][2];
      PRD_A(a0, 0, 0); PRD_B(b0, 0, 0); PSTG_A(0, 1, O1);
      PH_MID; PMFMAQ(a0, b0, 0, 0); PH_END;
      PRD_B(b1, 0, 2); PSTG_A(1, 1, O1);
      PH_MID; PMFMAQ(a0, b1, 0, 2); PH_END;
      PRD_A(a1, 0, 2); PSTG_B(0, E2);
      PH_MID; PMFMAQ(a1, b1, 2, 2); PH_END;
      PH_MID; PMFMAQ(a1, b0, 2, 0);
      __builtin_amdgcn_s_setprio(0);
      __builtin_amdgcn_sched_barrier(0);
      asm volatile("s_waitcnt vmcnt(2)" ::: "memory");   // tile O landed
      __builtin_amdgcn_s_barrier();
    }
    {   // tile O (buf1: A at +16384, B at +8192)
      bfrag8 a0[2][2], a1[2][2], b0[2][2], b1[2][2];
      PRD_A(a0, 16384, 0); PRD_B(b0, 8192, 0); PSTG_A(0, 0, E2);
      PH_MID; PMFMAQ(a0, b0, 0, 0); PH_END;
      PRD_B(b1, 8192, 2); PSTG_A(1, 0, E2);
      PH_MID; PMFMAQ(a0, b1, 0, 2); PH_END;
      PRD_A(a1, 16384, 2); PSTG_B(1, O2);
      PH_MID; PMFMAQ(a1, b1, 2, 2); PH_END;
      PH_MID; PMFMAQ(a1, b0, 2, 0);
      __builtin_amdgcn_s_setprio(0);
      __builtin_amdgcn_sched_barrier(0);
      asm volatile("s_waitcnt vmcnt(2)" ::: "memory");   // tile E+2 landed
      __builtin_amdgcn_s_barrier();
    }
  }
  {   // peeled last iteration: tiles NT-2 (buf0), NT-1 (buf1)
    const int O1 = NT - 1;
    {
      bfrag8 a0[2][2], a1[2][2], b0[2][2], b1[2][2];
      PRD_A(a0, 0, 0); PRD_B(b0, 0, 0); PSTG_A(0, 1, O1);
      PH_MID; PMFMAQ(a0, b0, 0, 0); PH_END;
      PRD_B(b1, 0, 2); PSTG_A(1, 1, O1);
      PH_MID; PMFMAQ(a0, b1, 0, 2); PH_END;
      PRD_A(a1, 0, 2);
      PH_MID; PMFMAQ(a1, b1, 2, 2); PH_END;
      PH_MID; PMFMAQ(a1, b0, 2, 0);
      __builtin_amdgcn_s_setprio(0);
      __builtin_amdgcn_sched_barrier(0);
      asm volatile("s_waitcnt vmcnt(0)" ::: "memory");   // tile NT-1 landed
      __builtin_amdgcn_s_barrier();
    }
    {
      bfrag8 a0[2][2], a1[2][2], b0[2][2], b1[2][2];
      PRD_A(a0, 16384, 0); PRD_B(b0, 8192, 0);
      PH_MID; PMFMAQ(a0, b0, 0, 0); PH_END;
      PRD_B(b1, 8192, 2);
      PH_MID; PMFMAQ(a0, b1, 0, 2); PH_END;
      PRD_A(a1, 16384, 2);
      PH_MID; PMFMAQ(a1, b1, 2, 2); PH_END;
      PH_MID; PMFMAQ(a1, b0, 2, 0);
      __builtin_amdgcn_s_setprio(0);
    }
  }
#undef PH_MID
#undef PH_END
#undef PMFMAQ
#undef PRD_A
#undef PRD_B
#undef PSTG_A
#undef PSTG_B

  // Epilogue: C/D layout col=lane&15, row=(lane>>4)*4+reg  [m89-verified]
#pragma unroll
  for (int m = 0; m < 4; ++m) {
    float inv[4];
#pragma unroll
    for (int r = 0; r < 4; ++r)
      inv[r] = 1.0f / lz[bm + wm * 64 + m * 16 + lq * 4 + r];
#pragma unroll
    for (int n = 0; n < 4; ++n) {
      const long mm = bm + wm * 64 + m * 16 + lq * 4;
      const long nn = bn + wn * 64 + n * 16 + ln;
#pragma unroll
      for (int r = 0; r < 4; ++r)
        C[(mm + r) * 1024l + nn] = acc[m][n][r] * inv[r];
    }
  }
}

extern "C" void kernel_launch(void* const* d_in, const int* in_sizes, int n_in,
                              void* d_out, int out_size, void* d_ws, size_t ws_size,
                              hipStream_t stream) {
  const float* q_in = (const float*)d_in[0];
  const float* k_in = (const float*)d_in[1];
  const float* v_in = (const float*)d_in[2];
  const float* wq   = (const float*)d_in[3];
  const float* wk   = (const float*)d_in[4];
  const float* wv   = (const float*)d_in[5];
  float* out = (float*)d_out;

  const long NXH = (long)BATCH * SLEN * HID;   // 8,388,608
  const long NW  = (long)HID * HID;            // 1,048,576

  unsigned short* ws = (unsigned short*)d_ws;
  unsigned short* Xq  = ws;              // cast dst region is contiguous Xq..Wvb
  unsigned short* Xk  = Xq  + NXH;
  unsigned short* Xv  = Xk  + NXH;
  unsigned short* Wqb = Xv  + NXH;
  unsigned short* Wkb = Wqb + NW;
  unsigned short* Wvb = Wkb + NW;
  unsigned short* Qb  = Wvb + NW;
  unsigned short* Kb  = Qb  + NXH;
  unsigned short* Vt  = Kb  + NXH;       // Vt[h][b*S+s], ld = 8192
  float*          lsum = (float*)(Vt + NXH);   // 8192 fp32 row sums
  unsigned short* P   = Xq;              // 16.8M elems, aliases Xq+Xk (dead by then)

  static bool attr_done = false;
  if (!attr_done) {
    hipFuncSetAttribute(reinterpret_cast<const void*>(scores256),
                        hipFuncAttributeMaxDynamicSharedMemorySize, 131072);
    hipFuncSetAttribute(reinterpret_cast<const void*>(pv256),
                        hipFuncAttributeMaxDynamicSharedMemorySize, 98304);
    attr_done = true;
  }

  // 1. fused cast (28.3M elems) + lsum zeroing
  cast_all<<<dim3(27648), dim3(256), 0, stream>>>(q_in, k_in, v_in, wq, wk, wv,
                                                  (us4*)ws, lsum);

  // 2. all three projections in ONE dispatch (r0-proven 128^2, 1536 jobs)
  proj3<<<dim3(1536), dim3(256), 0, stream>>>(Xq, Wqb, Xk, Wkb, Xv, Wvb,
                                              Qb, Kb, Vt);

  // 3. scores+exp+rowsums, 256^2 core (256 blocks = 1/CU)
  scores256<<<dim3(8, 8, BATCH), dim3(512), 131072, stream>>>(Qb, Kb, P, lsum);

  // 4. PV on the 256x128 8-phase core (256 blocks = 1/CU)
  pv256<<<dim3(8, 8, BATCH), dim3(512), 98304, stream>>>(P, Vt, out, lsum);
}

// Round 8
// 276.388 us; speedup vs baseline: 1.6404x; 1.0153x over previous
//
#include <hip/hip_runtime.h>
#include <hip/hip_bf16.h>
#include <stdint.h>

// Problem constants: B=4, S=2048, H=1024
#define BATCH 4
#define SLEN  2048
#define HID   1024

typedef __attribute__((ext_vector_type(8))) short bfrag8;   // 8 bf16 (4 VGPRs)
typedef __attribute__((ext_vector_type(4))) float facc4;    // 4 fp32 acc
typedef __attribute__((ext_vector_type(4))) unsigned short us4;

__device__ __forceinline__ unsigned short f2b(float f) {
  union { float f; unsigned int i; } x; x.f = f;
  unsigned int r = x.i + 0x7FFFu + ((x.i >> 16) & 1u);  // RNE
  return (unsigned short)(r >> 16);
}

__device__ __forceinline__ void gl_lds16(const void* g, void* l) {
  __builtin_amdgcn_global_load_lds(
      (const __attribute__((address_space(1))) void*)g,
      (__attribute__((address_space(3))) void*)l, 16, 0, 0);
}

// ------------- fused fp32 -> bf16 cast of all six inputs + lsum zero -------
// At BW ceiling: 170 MB / ~27 us = 6.3 TB/s. [measured r0-r6]
__global__ __launch_bounds__(256) void cast_all(
    const float* __restrict__ q, const float* __restrict__ k,
    const float* __restrict__ v, const float* __restrict__ wq,
    const float* __restrict__ wk, const float* __restrict__ wv,
    us4* __restrict__ dst, float* __restrict__ lsum) {
  if (blockIdx.x < 8) {
    float4 z = {0.f, 0.f, 0.f, 0.f};
    ((float4*)lsum)[blockIdx.x * 256 + threadIdx.x] = z;
  }
  const long i = (long)blockIdx.x * 256 + threadIdx.x;
  const long S1 = 2097152, S2 = 4194304, S3 = 6291456,
             S4 = 6553600, S5 = 6815744;
  const float4* src; long off;
  if (i < S2) {
    if (i < S1) { src = (const float4*)q;  off = i; }
    else        { src = (const float4*)k;  off = i - S1; }
  } else if (i < S3) { src = (const float4*)v;  off = i - S2; }
  else if   (i < S4) { src = (const float4*)wq; off = i - S3; }
  else if   (i < S5) { src = (const float4*)wk; off = i - S4; }
  else               { src = (const float4*)wv; off = i - S5; }
  float4 x = src[off];
  us4 o;
  o.x = f2b(x.x); o.y = f2b(x.y); o.z = f2b(x.z); o.w = f2b(x.w);
  dst[i] = o;
}

// ============ fused QKV projection: r0-proven 128^2 core (912 TF) =========
// Session A/B matrix (r0-r6): this core beats every 8-phase 256-wide variant
// for proj (57us/912TF vs 61-78us) — cross-block overlap at 2-3 blocks/CU
// outperforms explicit pipelining at 1 block/CU for this K=1024 shape.
__global__ __launch_bounds__(256) void proj3(
    const unsigned short* __restrict__ Xq, const unsigned short* __restrict__ Wqb,
    const unsigned short* __restrict__ Xk, const unsigned short* __restrict__ Wkb,
    const unsigned short* __restrict__ Xv, const unsigned short* __restrict__ Wvb,
    unsigned short* __restrict__ Qb, unsigned short* __restrict__ Kb,
    unsigned short* __restrict__ Vt) {
  const int pid = blockIdx.x;
  const int p2     = (pid & 7) * 192 + (pid >> 3);  // XCD-contiguous
  const int g      = p2 >> 9;                       // 0:Q 1:K 2:Vt
  const int within = p2 & 511;

  const unsigned short* A; const unsigned short* B; unsigned short* C;
  long bm, bn; int ldc_;
  if (g == 0)      { A = Xq; B = Wqb; C = Qb; }
  else if (g == 1) { A = Xk; B = Wkb; C = Kb; }
  else             { A = Wvb; B = Xv; C = Vt; }
  if (g < 2) {   // nbm=64, nbn=8, GROUP=4
    const int gid = within >> 5, rem = within & 31;
    bm = (long)(gid * 4 + (rem & 3)) * 128;
    bn = (long)(rem >> 2) * 128;
    ldc_ = 1024;
  } else {       // nbm=8, nbn=64, GROUP=4
    const int gid = within >> 8, rem = within & 255;
    bm = (long)(gid * 4 + (rem & 3)) * 128;
    bn = (long)(rem >> 2) * 128;
    ldc_ = 8192;
  }

  __shared__ __align__(16) unsigned short As[128 * 64];
  __shared__ __align__(16) unsigned short Bs[128 * 64];

  const int tid  = threadIdx.x;
  const int lane = tid & 63;
  const int wave = tid >> 6;
  const int wr   = (wave >> 1) * 64;
  const int wc   = (wave & 1) * 64;
  const int ln   = lane & 15;
  const int lq   = lane >> 4;
  const int swz  = ln & 7;

  facc4 acc[4][4] = {};

  const unsigned short* ap[4]; const unsigned short* bp[4];
  unsigned short* asd[4]; unsigned short* bsd[4];
#pragma unroll
  for (int j = 0; j < 4; ++j) {
    const int c   = j * 256 + tid;
    const int row = c >> 3;
    const int src = ((c & 7) ^ (row & 7)) * 8;
    ap[j]  = A + (bm + row) * 1024 + src;
    bp[j]  = B + (bn + row) * 1024 + src;
    asd[j] = &As[c * 8];
    bsd[j] = &Bs[c * 8];
  }

  for (int k0 = 0; k0 < 1024; k0 += 64) {
#pragma unroll
    for (int j = 0; j < 4; ++j) { gl_lds16(ap[j], asd[j]); ap[j] += 64; }
#pragma unroll
    for (int j = 0; j < 4; ++j) { gl_lds16(bp[j], bsd[j]); bp[j] += 64; }
    __syncthreads();

#pragma unroll
    for (int kk = 0; kk < 2; ++kk) {
      bfrag8 af[4], bfr[4];
#pragma unroll
      for (int i = 0; i < 4; ++i)
        af[i] = *(const bfrag8*)&As[(wr + i * 16 + ln) * 64 + ((kk * 4 + lq) ^ swz) * 8];
#pragma unroll
      for (int j = 0; j < 4; ++j)
        bfr[j] = *(const bfrag8*)&Bs[(wc + j * 16 + ln) * 64 + ((kk * 4 + lq) ^ swz) * 8];
#pragma unroll
      for (int i = 0; i < 4; ++i)
#pragma unroll
        for (int j = 0; j < 4; ++j)
          acc[i][j] = __builtin_amdgcn_mfma_f32_16x16x32_bf16(af[i], bfr[j], acc[i][j], 0, 0, 0);
    }
    __syncthreads();
  }

  // Epilogue: C/D layout col=lane&15, row=(lane>>4)*4+reg  [m89-verified]
#pragma unroll
  for (int i = 0; i < 4; ++i)
#pragma unroll
    for (int j = 0; j < 4; ++j) {
      const long m = bm + wr + i * 16 + lq * 4;
      const long n = bn + wc + j * 16 + ln;
#pragma unroll
      for (int r = 0; r < 4; ++r)
        C[(m + r) * (long)ldc_ + n] = f2b(acc[i][j][r]);
    }
}

// ================= 256x256 / BK=64 core — 8-phase (scores only) ===========
// Session A/B: this core wins ONLY for scores (heavy exp/store epilogue +
// exact 1/CU packing): ~42us/820TF vs 56us/610TF on the 128^2 core.
template <int NT>
__device__ __forceinline__ void core256(
    const unsigned short* __restrict__ A, const unsigned short* __restrict__ B,
    const int lda, const int ldb,
    unsigned short* __restrict__ As, unsigned short* __restrict__ Bs,
    facc4 (&acc)[8][4]) {
  const int tid  = threadIdx.x;          // 0..511
  const int lane = tid & 63;
  const int wave = tid >> 6;             // 0..7
  const int wm = wave >> 2;              // 0..1
  const int wn = wave & 3;               // 0..3
  const int ln = lane & 15;
  const int lq = lane >> 4;
  const int swz = ln & 7;

  const int row0 = tid >> 3;
  const int blk  = (tid & 7) ^ (row0 & 7);
  const unsigned short* pA = A + (long)row0 * lda + blk * 8;
  const unsigned short* pB = B + (long)row0 * ldb + blk * 8;
  const long a64 = 64l * lda, b64 = 64l * ldb;
  unsigned short* dA = As + tid * 8;
  unsigned short* dB = Bs + tid * 8;

#define STG_A(h, b, t) do { const unsigned short* g_ = pA + (h) * (a64 * 2) + (long)(t) * 64; \
    gl_lds16(g_,       dA + (b) * 16384 + (h) * 8192); \
    gl_lds16(g_ + a64, dA + (b) * 16384 + (h) * 8192 + 4096); } while (0)
#define STG_B(h, b, t) do { const unsigned short* g_ = pB + (h) * (b64 * 2) + (long)(t) * 64; \
    gl_lds16(g_,       dB + (b) * 16384 + (h) * 8192); \
    gl_lds16(g_ + b64, dB + (b) * 16384 + (h) * 8192 + 4096); } while (0)

  const int o0 = (lq ^ swz) * 8;
  const int o1 = ((4 + lq) ^ swz) * 8;
  const int aOfs = wm * 8192 + ln * 64;
  const int bOfs = (wn >> 1) * 8192 + ((wn & 1) * 64 + ln) * 64;

#define RD_A4(dst, bufb, mb) do { \
  _Pragma("unroll") for (int m_ = 0; m_ < 4; ++m_) { \
    dst[m_][0] = *(const bfrag8*)(As + (bufb) + aOfs + ((mb) + m_) * 1024 + o0); \
    dst[m_][1] = *(const bfrag8*)(As + (bufb) + aOfs + ((mb) + m_) * 1024 + o1); \
  } } while (0)
#define RD_B2(dst, bufb, nb) do { \
  _Pragma("unroll") for (int n_ = 0; n_ < 2; ++n_) { \
    dst[n_][0] = *(const bfrag8*)(Bs + (bufb) + bOfs + ((nb) + n_) * 1024 + o0); \
    dst[n_][1] = *(const bfrag8*)(Bs + (bufb) + bOfs + ((nb) + n_) * 1024 + o1); \
  } } while (0)

#define MFMAQ(AF, BF, MO, NO) do { \
  _Pragma("unroll") for (int m_ = 0; m_ < 4; ++m_) \
  _Pragma("unroll") for (int n_ = 0; n_ < 2; ++n_) { \
    acc[(MO)+m_][(NO)+n_] = __builtin_amdgcn_mfma_f32_16x16x32_bf16( \
        AF[m_][0], BF[n_][0], acc[(MO)+m_][(NO)+n_], 0, 0, 0); \
    acc[(MO)+m_][(NO)+n_] = __builtin_amdgcn_mfma_f32_16x16x32_bf16( \
        AF[m_][1], BF[n_][1], acc[(MO)+m_][(NO)+n_], 0, 0, 0); \
  } } while (0)

#define PH_MID \
  __builtin_amdgcn_s_barrier(); \
  asm volatile("s_waitcnt lgkmcnt(0)" ::: "memory"); \
  __builtin_amdgcn_sched_barrier(0); \
  __builtin_amdgcn_s_setprio(1)
#define PH_END \
  __builtin_amdgcn_s_setprio(0); \
  __builtin_amdgcn_sched_barrier(0); \
  __builtin_amdgcn_s_barrier()

  STG_A(0, 0, 0); STG_A(1, 0, 0); STG_B(0, 0, 0); STG_B(1, 0, 0);
  STG_B(0, 1, 1); STG_B(1, 1, 1);
  asm volatile("s_waitcnt vmcnt(4)" ::: "memory");
  __builtin_amdgcn_s_barrier();

  constexpr int NI = NT / 2;
#pragma unroll 1
  for (int i = 0; i < NI - 1; ++i) {
    const int O1 = 2 * i + 1, E2 = 2 * i + 2, O2 = 2 * i + 3;
    {
      bfrag8 a0[4][2], a1[4][2], b0[2][2], b1[2][2];
      RD_A4(a0, 0, 0); RD_B2(b0, 0, 0); STG_A(0, 1, O1);
      PH_MID; MFMAQ(a0, b0, 0, 0); PH_END;
      RD_B2(b1, 0, 2); STG_A(1, 1, O1);
      PH_MID; MFMAQ(a0, b1, 0, 2); PH_END;
      RD_A4(a1, 0, 4); STG_B(0, 0, E2);
      PH_MID; MFMAQ(a1, b1, 4, 2); PH_END;
      STG_B(1, 0, E2);
      PH_MID; MFMAQ(a1, b0, 4, 0);
      __builtin_amdgcn_s_setprio(0);
      __builtin_amdgcn_sched_barrier(0);
      asm volatile("s_waitcnt vmcnt(4)" ::: "memory");
      __builtin_amdgcn_s_barrier();
    }
    {
      bfrag8 a0[4][2], a1[4][2], b0[2][2], b1[2][2];
      RD_A4(a0, 16384, 0); RD_B2(b0, 16384, 0); STG_A(0, 0, E2);
      PH_MID; MFMAQ(a0, b0, 0, 0); PH_END;
      RD_B2(b1, 16384, 2); STG_A(1, 0, E2);
      PH_MID; MFMAQ(a0, b1, 0, 2); PH_END;
      RD_A4(a1, 16384, 4); STG_B(0, 1, O2);
      PH_MID; MFMAQ(a1, b1, 4, 2); PH_END;
      STG_B(1, 1, O2);
      PH_MID; MFMAQ(a1, b0, 4, 0);
      __builtin_amdgcn_s_setprio(0);
      __builtin_amdgcn_sched_barrier(0);
      asm volatile("s_waitcnt vmcnt(4)" ::: "memory");
      __builtin_amdgcn_s_barrier();
    }
  }
  {
    const int O1 = NT - 1;
    {
      bfrag8 a0[4][2], a1[4][2], b0[2][2], b1[2][2];
      RD_A4(a0, 0, 0); RD_B2(b0, 0, 0); STG_A(0, 1, O1);
      PH_MID; MFMAQ(a0, b0, 0, 0); PH_END;
      RD_B2(b1, 0, 2); STG_A(1, 1, O1);
      PH_MID; MFMAQ(a0, b1, 0, 2); PH_END;
      RD_A4(a1, 0, 4);
      PH_MID; MFMAQ(a1, b1, 4, 2); PH_END;
      PH_MID; MFMAQ(a1, b0, 4, 0);
      __builtin_amdgcn_s_setprio(0);
      __builtin_amdgcn_sched_barrier(0);
      asm volatile("s_waitcnt vmcnt(0)" ::: "memory");
      __builtin_amdgcn_s_barrier();
    }
    {
      bfrag8 a0[4][2], a1[4][2], b0[2][2], b1[2][2];
      RD_A4(a0, 16384, 0); RD_B2(b0, 16384, 0);
      PH_MID; MFMAQ(a0, b0, 0, 0); PH_END;
      RD_B2(b1, 16384, 2);
      PH_MID; MFMAQ(a0, b1, 0, 2); PH_END;
      RD_A4(a1, 16384, 4);
      PH_MID; MFMAQ(a1, b1, 4, 2); PH_END;
      PH_MID; MFMAQ(a1, b0, 4, 0);
      __builtin_amdgcn_s_setprio(0);
    }
  }
#undef PH_MID
#undef PH_END
#undef MFMAQ
#undef RD_A4
#undef RD_B2
#undef STG_A
#undef STG_B
}

// ============ scores on the 256^2 core: P = exp(Q.K^T/32), lsum += ========
// 256 blocks total (8x8 tiles x 4 batches) = exactly 1 per CU.
// (r7 __exp2f micro-opt reverted: __exp2f is not a HIP device symbol —
//  collides with glibc math.h. __expf is the proven spelling.)
__global__ __launch_bounds__(512, 2) void scores256(
    const unsigned short* __restrict__ Q, const unsigned short* __restrict__ Kb,
    unsigned short* __restrict__ P, float* __restrict__ lsum) {
  extern __shared__ unsigned short smem[];
  unsigned short* As = smem;
  unsigned short* Bs = smem + 32768;

  const long z = blockIdx.z;
  const int pid = blockIdx.y * 8 + blockIdx.x;
  const int p2  = (pid & 7) * 8 + (pid >> 3);   // XCD gets one bm row-panel
  const long bm = (long)(p2 >> 3) * 256;
  const long bn = (long)(p2 & 7) * 256;

  const long SH = (long)SLEN * HID, SS = (long)SLEN * SLEN;
  facc4 acc[8][4] = {};
  core256<HID / 64>(Q + z * SH + bm * 1024, Kb + z * SH + bn * 1024, 1024, 1024,
                    As, Bs, acc);

  unsigned short* Pz = P + z * SS;
  float* lz = lsum + z * SLEN;
  const int lane = threadIdx.x & 63, wave = threadIdx.x >> 6;
  const int wm = wave >> 2, wn = wave & 3;
  const int ln = lane & 15, lq = lane >> 4;
#pragma unroll
  for (int m = 0; m < 8; ++m) {
#pragma unroll
    for (int r = 0; r < 4; ++r) {
      const long q = bm + wm * 128 + m * 16 + lq * 4 + r;
      float rowsum = 0.f;
#pragma unroll
      for (int n = 0; n < 4; ++n) {
        const long kcol = bn + wn * 64 + n * 16 + ln;
        float e = __expf(acc[m][n][r] * 0.03125f);
        Pz[q * (long)SLEN + kcol] = f2b(e);
        rowsum += e;
      }
      rowsum += __shfl_xor(rowsum, 1, 64);
      rowsum += __shfl_xor(rowsum, 2, 64);
      rowsum += __shfl_xor(rowsum, 4, 64);
      rowsum += __shfl_xor(rowsum, 8, 64);
      if (ln == 0) atomicAdd(&lz[q], rowsum);
    }
  }
}

// ---------------- PV: r4-proven 128^2 core (best measured PV) --------------
// out[b][q][h] = (1/lsum[b,q]) * sum_k P[b,q,k] * Vt[h][b*S+k]
// r6 A/B: 256x128 8-phase variant was neutral-to-worse; this is the keeper.
// Micro-opt kept: v_rcp_f32 for 1/lsum (compiled clean in r7; 1-ulp).
__global__ __launch_bounds__(256) void pv128(
    const unsigned short* __restrict__ P, const unsigned short* __restrict__ Vt,
    float* __restrict__ out, const float* __restrict__ lsum) {
  const long z = blockIdx.z;
  const unsigned short* A = P  + z * (long)SLEN * SLEN;   // lda 2048
  const unsigned short* B = Vt + z * SLEN;                // ldb 8192
  float* C = out + z * (long)SLEN * HID;                  // ldc 1024
  const float* lz = lsum + z * SLEN;

  const int nbm = gridDim.x, nbn = gridDim.y;             // 16 x 8
  const int nb  = nbm * nbn;
  const int pid = blockIdx.y * nbm + blockIdx.x;
  const int p2  = (pid & 7) * (nb >> 3) + (pid >> 3);
  const int gsize = 4 * nbn;
  const int gid   = p2 / gsize;
  const int rem   = p2 - gid * gsize;
  const long bm = (long)(gid * 4 + (rem & 3)) * 128;
  const long bn = (long)(rem >> 2) * 128;

  __shared__ __align__(16) unsigned short As[128 * 64];
  __shared__ __align__(16) unsigned short Bs[128 * 64];

  const int tid  = threadIdx.x;
  const int lane = tid & 63;
  const int wave = tid >> 6;
  const int wr   = (wave >> 1) * 64;
  const int wc   = (wave & 1) * 64;
  const int ln   = lane & 15;
  const int lq   = lane >> 4;
  const int swz  = ln & 7;

  facc4 acc[4][4] = {};

  const unsigned short* ap[4]; const unsigned short* bp[4];
  unsigned short* asd[4]; unsigned short* bsd[4];
#pragma unroll
  for (int j = 0; j < 4; ++j) {
    const int c   = j * 256 + tid;
    const int row = c >> 3;
    const int src = ((c & 7) ^ (row & 7)) * 8;
    ap[j]  = A + (bm + row) * 2048l + src;
    bp[j]  = B + (bn + row) * 8192l + src;
    asd[j] = &As[c * 8];
    bsd[j] = &Bs[c * 8];
  }

  for (int k0 = 0; k0 < 2048; k0 += 64) {
#pragma unroll
    for (int j = 0; j < 4; ++j) { gl_lds16(ap[j], asd[j]); ap[j] += 64; }
#pragma unroll
    for (int j = 0; j < 4; ++j) { gl_lds16(bp[j], bsd[j]); bp[j] += 64; }
    __syncthreads();

#pragma unroll
    for (int kk = 0; kk < 2; ++kk) {
      bfrag8 af[4], bfr[4];
#pragma unroll
      for (int i = 0; i < 4; ++i)
        af[i] = *(const bfrag8*)&As[(wr + i * 16 + ln) * 64 + ((kk * 4 + lq) ^ swz) * 8];
#pragma unroll
      for (int j = 0; j < 4; ++j)
        bfr[j] = *(const bfrag8*)&Bs[(wc + j * 16 + ln) * 64 + ((kk * 4 + lq) ^ swz) * 8];
#pragma unroll
      for (int i = 0; i < 4; ++i)
#pragma unroll
        for (int j = 0; j < 4; ++j)
          acc[i][j] = __builtin_amdgcn_mfma_f32_16x16x32_bf16(af[i], bfr[j], acc[i][j], 0, 0, 0);
    }
    __syncthreads();
  }

  float inv[16];
#pragma unroll
  for (int i = 0; i < 4; ++i)
#pragma unroll
    for (int r = 0; r < 4; ++r)
      inv[i * 4 + r] = __builtin_amdgcn_rcpf(lz[bm + wr + i * 16 + lq * 4 + r]);
#pragma unroll
  for (int i = 0; i < 4; ++i)
#pragma unroll
    for (int j = 0; j < 4; ++j) {
      const long m = bm + wr + i * 16 + lq * 4;
      const long n = bn + wc + j * 16 + ln;
#pragma unroll
      for (int r = 0; r < 4; ++r)
        C[(m + r) * 1024l + n] = acc[i][j][r] * inv[i * 4 + r];
    }
}

extern "C" void kernel_launch(void* const* d_in, const int* in_sizes, int n_in,
                              void* d_out, int out_size, void* d_ws, size_t ws_size,
                              hipStream_t stream) {
  const float* q_in = (const float*)d_in[0];
  const float* k_in = (const float*)d_in[1];
  const float* v_in = (const float*)d_in[2];
  const float* wq   = (const float*)d_in[3];
  const float* wk   = (const float*)d_in[4];
  const float* wv   = (const float*)d_in[5];
  float* out = (float*)d_out;

  const long NXH = (long)BATCH * SLEN * HID;   // 8,388,608
  const long NW  = (long)HID * HID;            // 1,048,576

  unsigned short* ws = (unsigned short*)d_ws;
  unsigned short* Xq  = ws;              // cast dst region is contiguous Xq..Wvb
  unsigned short* Xk  = Xq  + NXH;
  unsigned short* Xv  = Xk  + NXH;
  unsigned short* Wqb = Xv  + NXH;
  unsigned short* Wkb = Wqb + NW;
  unsigned short* Wvb = Wkb + NW;
  unsigned short* Qb  = Wvb + NW;
  unsigned short* Kb  = Qb  + NXH;
  unsigned short* Vt  = Kb  + NXH;       // Vt[h][b*S+s], ld = 8192
  float*          lsum = (float*)(Vt + NXH);   // 8192 fp32 row sums
  unsigned short* P   = Xq;              // 16.8M elems, aliases Xq+Xk (dead by then)

  static bool attr_done = false;
  if (!attr_done) {
    (void)hipFuncSetAttribute(reinterpret_cast<const void*>(scores256),
                              hipFuncAttributeMaxDynamicSharedMemorySize, 131072);
    attr_done = true;
  }

  // 1. fused cast (28.3M elems) + lsum zeroing — HBM-bound floor (~27 us)
  cast_all<<<dim3(27648), dim3(256), 0, stream>>>(q_in, k_in, v_in, wq, wk, wv,
                                                  (us4*)ws, lsum);

  // 2. all three projections in ONE dispatch (r0-proven 128^2, 1536 jobs)
  proj3<<<dim3(1536), dim3(256), 0, stream>>>(Xq, Wqb, Xk, Wkb, Xv, Wvb,
                                              Qb, Kb, Vt);

  // 3. scores+exp+rowsums, 256^2 8-phase core (256 blocks = 1/CU)
  scores256<<<dim3(8, 8, BATCH), dim3(512), 131072, stream>>>(Qb, Kb, P, lsum);

  // 4. PV on the r4-proven 128^2 core (512 blocks, 2/CU)
  pv128<<<dim3(16, 8, BATCH), dim3(256), 0, stream>>>(P, Vt, out, lsum);
}